// Round 19
// baseline (1047.720 us; speedup 1.0000x reference)
//
#include <hip/hip_runtime.h>
#include <math.h>

#define NPTS 8192
#define CHN 128
#define NLAYER 12
#define LDH 136   // fp16 LDS row stride (128 + 8): 272 B = 16-B aligned (verified layout)

typedef __attribute__((ext_vector_type(8))) _Float16 f16x8;
typedef __attribute__((ext_vector_type(4))) float f32x4;

__device__ inline void split_f16(float x, _Float16* hi, _Float16* lo) {
  _Float16 h = (_Float16)x;            // RNE
  *hi = h;
  *lo = (_Float16)(x - (float)h);      // residual
}

union U2h { unsigned int u; _Float16 f[2]; };
union U4h { uint2 u; _Float16 f[4]; };

// ---- split W1s/W2s fp32 -> (hi,lo) fp16; conv c = 2*layer (W1) / 2*layer+1 (W2), [o][c] ----
// (lo plane still produced; unused by the mlp kernel)
__global__ void prep_w_kernel(const float* __restrict__ W1s,
                              const float* __restrict__ W2s,
                              _Float16* __restrict__ Whi,
                              _Float16* __restrict__ Wlo) {
  int idx = blockIdx.x * 256 + threadIdx.x;
  if (idx >= 24 * 128 * 128) return;
  int conv = idx >> 14;
  int r = idx & 16383;
  const float* src = (conv & 1) ? (W2s + ((size_t)(conv >> 1) << 14))
                                : (W1s + ((size_t)(conv >> 1) << 14));
  _Float16 h, l;
  split_f16(src[r], &h, &l);
  Whi[idx] = h;
  Wlo[idx] = l;
}

// ---------------- MFMA MLP + weighted Gram partials ----------------
// R19 = R14 champion shell (128-pt tile, grid 4096, 256 thr, W-register prefetch)
// with the MFMA wave shape remapped to R2's VERIFIED mt=4/nt=2 decomposition:
//   wave = 64 out-ch x 32 pts  (mo0 = (wv&1)*64, pt0 = (wv>>1)*32)
//   - LDS B-reads per conv-block HALVE vs R14 (128 -> 64 b128): each B fragment
//     feeds 4 mt tiles. R14 budget shows LDS pipe ~80% busy -> attacks the wall.
//   - A-loads/conv-block 32 -> 64 (2x duplication across pt-groups) -- R2's
//     original perf failure, now neutralized by the cross-phase prefetch.
//   - MFMA count & per-output K-accumulation order unchanged -> absmax identical.
// First/final/gram = R14's verified code (fc0 = wv*32 mapping), untouched.
__global__ __launch_bounds__(256, 2) void mlp_xwx_kernel(
    const float* __restrict__ xc,            // (B,4,N)
    const float* __restrict__ Wfirst,        // (128,4) fp32
    const float* __restrict__ bfirst,        // (128)
    const _Float16* __restrict__ Whi,        // (24,128,128)
    const _Float16* __restrict__ Wlo,        // (24,128,128) unused
    const float* __restrict__ b1s,           // (12,128)
    const float* __restrict__ b2s,           // (12,128)
    const float* __restrict__ Wfinal,        // (128)
    const float* __restrict__ bfinal,        // (1)
    float* __restrict__ partial) {           // (8192,45)
  __shared__ __align__(16) _Float16 Hh[128 * LDH];
  __shared__ __align__(16) _Float16 Yh[128 * LDH];
  __shared__ float red[4][64];
  const int tid = threadIdx.x;
  const int lane = tid & 63;
  const int wv = tid >> 6;                // 0..3
  const int l16 = lane & 15;
  const int quad = lane >> 4;
  const int fc0 = wv << 5;                // first/final-layer 32-channel base (R14 verified)
  const int mo0 = (wv & 1) << 6;          // MFMA 64-channel group base (R2 verified)
  const int pt0 = (wv >> 1) << 5;         // MFMA 32-point group within 64-pt subtile
  const int b = blockIdx.x >> 6;          // 4096 blocks / 64 per image
  const int n0 = (blockIdx.x & 63) << 7;  // 128 points per block

  const float* xb = xc + ((size_t)b * 4) * NPTS + n0 + lane;
  float x1[2], x2[2], y1[2], y2[2];
  #pragma unroll
  for (int s = 0; s < 2; ++s) {
    x1[s] = xb[s * 64 + 0 * NPTS];
    x2[s] = xb[s * 64 + 1 * NPTS];
    y1[s] = xb[s * 64 + 2 * NPTS];
    y2[s] = xb[s * 64 + 3 * NPTS];
  }

  // A-frag base: W[mo0 + l16 + 16*mt][quad*8 + 32*kt + j]
  const size_t arow = (size_t)(mo0 + l16) * CHN + (size_t)quad * 8;

  // ---- W register double-buffer; prologue loads wA = W1[0] (overlaps first layer) ----
  f16x8 wA[4][4], wB[4][4];
  {
    const _Float16* W1h = Whi;
    #pragma unroll
    for (int mt = 0; mt < 4; ++mt)
      #pragma unroll
      for (int kt = 0; kt < 4; ++kt)
        wA[mt][kt] = *(const f16x8*)(W1h + arow + (size_t)mt * 16 * CHN + kt * 32);
  }

  // ---- first layer (4 -> 128) on VALU fp32: wave wv does channels fc0..fc0+32, both sub-tiles ----
  #pragma unroll
  for (int s = 0; s < 2; ++s) {
    #pragma unroll
    for (int j = 0; j < 32; j += 2) {
      int c = fc0 + j;
      float h0 = bfirst[c] + Wfirst[c * 4 + 0] * x1[s] + Wfirst[c * 4 + 1] * x2[s] +
                 Wfirst[c * 4 + 2] * y1[s] + Wfirst[c * 4 + 3] * y2[s];
      float h1 = bfirst[c + 1] + Wfirst[(c + 1) * 4 + 0] * x1[s] + Wfirst[(c + 1) * 4 + 1] * x2[s] +
                 Wfirst[(c + 1) * 4 + 2] * y1[s] + Wfirst[(c + 1) * 4 + 3] * y2[s];
      U2h ph;
      ph.f[0] = (_Float16)h0;
      ph.f[1] = (_Float16)h1;
      *(unsigned int*)&Hh[(s * 64 + lane) * LDH + c] = ph.u;
    }
  }
  __syncthreads();

  for (int layer = 0; layer < NLAYER; ++layer) {
    // ========== conv1 on both sub-tiles (uses wA); prefetch wB = W2[layer] ==========
    {
      const _Float16* W2h = Whi + ((size_t)(2 * layer + 1) << 14);
      #pragma unroll
      for (int mt = 0; mt < 4; ++mt)
        #pragma unroll
        for (int kt = 0; kt < 4; ++kt)
          wB[mt][kt] = *(const f16x8*)(W2h + arow + (size_t)mt * 16 * CHN + kt * 32);

      f32x4 bv[4];
      #pragma unroll
      for (int mt = 0; mt < 4; ++mt)
        bv[mt] = *(const f32x4*)(b1s + layer * CHN + mo0 + mt * 16 + quad * 4);

      #pragma unroll
      for (int s = 0; s < 2; ++s) {
        f32x4 acc[4][2];
        #pragma unroll
        for (int mt = 0; mt < 4; ++mt)
          #pragma unroll
          for (int nt = 0; nt < 2; ++nt)
            #pragma unroll
            for (int r = 0; r < 4; ++r) acc[mt][nt][r] = 0.0f;
        #pragma unroll
        for (int kt = 0; kt < 4; ++kt) {
          #pragma unroll
          for (int nt = 0; nt < 2; ++nt) {
            f16x8 bh = *(const f16x8*)&Hh[(s * 64 + pt0 + nt * 16 + l16) * LDH + kt * 32 + quad * 8];
            #pragma unroll
            for (int mt = 0; mt < 4; ++mt)
              acc[mt][nt] = __builtin_amdgcn_mfma_f32_16x16x32_f16(wA[mt][kt], bh, acc[mt][nt], 0, 0, 0);
          }
        }
        #pragma unroll
        for (int mt = 0; mt < 4; ++mt)
          #pragma unroll
          for (int nt = 0; nt < 2; ++nt) {
            int p = s * 64 + pt0 + nt * 16 + l16;
            int c = mo0 + mt * 16 + quad * 4;
            U4h ph;
            #pragma unroll
            for (int r = 0; r < 4; ++r)
              ph.f[r] = (_Float16)fmaxf(acc[mt][nt][r] + bv[mt][r], 0.0f);
            *(uint2*)&Yh[p * LDH + c] = ph.u;
          }
      }
    }
    __syncthreads();
    // ========== conv2 on both sub-tiles (uses wB); prefetch wA = W1[layer+1] ==========
    {
      if (layer + 1 < NLAYER) {
        const _Float16* W1h = Whi + ((size_t)(2 * layer + 2) << 14);
        #pragma unroll
        for (int mt = 0; mt < 4; ++mt)
          #pragma unroll
          for (int kt = 0; kt < 4; ++kt)
            wA[mt][kt] = *(const f16x8*)(W1h + arow + (size_t)mt * 16 * CHN + kt * 32);
      }

      f32x4 bv[4];
      #pragma unroll
      for (int mt = 0; mt < 4; ++mt)
        bv[mt] = *(const f32x4*)(b2s + layer * CHN + mo0 + mt * 16 + quad * 4);

      #pragma unroll
      for (int s = 0; s < 2; ++s) {
        f32x4 acc[4][2];
        #pragma unroll
        for (int mt = 0; mt < 4; ++mt)
          #pragma unroll
          for (int nt = 0; nt < 2; ++nt)
            #pragma unroll
            for (int r = 0; r < 4; ++r) acc[mt][nt][r] = 0.0f;
        #pragma unroll
        for (int kt = 0; kt < 4; ++kt) {
          #pragma unroll
          for (int nt = 0; nt < 2; ++nt) {
            f16x8 bh = *(const f16x8*)&Yh[(s * 64 + pt0 + nt * 16 + l16) * LDH + kt * 32 + quad * 8];
            #pragma unroll
            for (int mt = 0; mt < 4; ++mt)
              acc[mt][nt] = __builtin_amdgcn_mfma_f32_16x16x32_f16(wB[mt][kt], bh, acc[mt][nt], 0, 0, 0);
          }
        }
        #pragma unroll
        for (int mt = 0; mt < 4; ++mt)
          #pragma unroll
          for (int nt = 0; nt < 2; ++nt) {
            int p = s * 64 + pt0 + nt * 16 + l16;
            int c = mo0 + mt * 16 + quad * 4;
            U4h oh;
            oh.u = *(const uint2*)&Hh[p * LDH + c];
            U4h ph;
            #pragma unroll
            for (int r = 0; r < 4; ++r) {
              float v = fmaxf((float)oh.f[r] + acc[mt][nt][r] + bv[mt][r], 0.0f);
              ph.f[r] = (_Float16)v;
            }
            *(uint2*)&Hh[p * LDH + c] = ph.u;
          }
      }
    }
    __syncthreads();
  }

  // ---- final conv (128 -> 1) + weighted Gram, per sub-tile (R14-verified code) ----
  #pragma unroll
  for (int s = 0; s < 2; ++s) {
    {
      float part = 0.0f;
      #pragma unroll
      for (int j = 0; j < 4; ++j) {
        f16x8 kh = *(const f16x8*)&Hh[(s * 64 + lane) * LDH + fc0 + j * 8];
        #pragma unroll
        for (int e = 0; e < 8; ++e)
          part = fmaf(Wfinal[fc0 + j * 8 + e], (float)kh[e], part);
      }
      red[wv][lane] = part;
    }
    __syncthreads();
    if (wv == 0) {
      float logit = red[0][lane] + red[1][lane] + red[2][lane] + red[3][lane] + bfinal[0];
      float wgt = fmaxf(tanhf(logit), 0.0f);
      float X[9] = {y1[s] * x1[s], y1[s] * x2[s], y1[s], y2[s] * x1[s], y2[s] * x2[s], y2[s],
                    x1[s], x2[s], 1.0f};
      int k = 0;
      #pragma unroll
      for (int i = 0; i < 9; ++i) {
        #pragma unroll
        for (int j = i; j < 9; ++j) {
          float v = wgt * X[i] * X[j];
          #pragma unroll
          for (int off = 32; off > 0; off >>= 1) v += __shfl_down(v, off, 64);
          if (lane == 0) partial[((size_t)blockIdx.x * 2 + s) * 45 + k] = v;
          ++k;
        }
      }
    }
    __syncthreads();   // red reused by next sub-tile
  }
}

// ------------- deterministic fixed-order reduction of per-block partials -------------
__global__ void reduce_xwx_kernel(const float* __restrict__ partial,
                                  float* __restrict__ xwx) {
#pragma clang fp contract(off)
  int tid = blockIdx.x * 256 + threadIdx.x;
  if (tid >= 64 * 45) return;
  int b = tid / 45;
  int k = tid % 45;
  float s = 0.0f;
  for (int blk = 0; blk < 128; ++blk)
    s += partial[((size_t)b * 128 + blk) * 45 + k];
  xwx[tid] = s;
}

// -------- faithful LAPACK fp32 ssyevd path for 9x9 (ssytd2 + ssteqr('I') + Q) --------
__device__ inline float s_sign(float a, float b) { return (b >= 0.0f) ? fabsf(a) : -fabsf(a); }

__device__ inline float slapy2_(float x, float y) {
#pragma clang fp contract(off)
  float ax = fabsf(x), ay = fabsf(y);
  float w = ax > ay ? ax : ay;
  float z = ax > ay ? ay : ax;
  if (z == 0.0f) return w;
  float t = z / w;
  return w * sqrtf(1.0f + t * t);
}

// LAPACK >= 3.10 slartg (c >= 0 convention), fast path
__device__ inline void slartg_(float f, float g, float* c, float* s, float* r) {
#pragma clang fp contract(off)
  if (g == 0.0f) { *c = 1.0f; *s = 0.0f; *r = f; }
  else if (f == 0.0f) { *c = 0.0f; *s = s_sign(1.0f, g); *r = fabsf(g); }
  else {
    float f1 = fabsf(f);
    float d = sqrtf(f * f + g * g);
    *c = f1 / d;
    *r = s_sign(d, f);
    *s = g / (*r);
  }
}

__device__ void slaev2_(float a, float b, float c, float* rt1, float* rt2,
                        float* cs1, float* sn1) {
#pragma clang fp contract(off)
  float sm = a + c, df = a - c, adf = fabsf(df), tb = b + b, ab = fabsf(tb);
  float acmx, acmn;
  if (fabsf(a) > fabsf(c)) { acmx = a; acmn = c; } else { acmx = c; acmn = a; }
  float rt;
  if (adf > ab) { float t = ab / adf; rt = adf * sqrtf(1.0f + t * t); }
  else if (adf < ab) { float t = adf / ab; rt = ab * sqrtf(1.0f + t * t); }
  else rt = ab * sqrtf(2.0f);
  int sgn1;
  if (sm < 0.0f) { *rt1 = 0.5f * (sm - rt); sgn1 = -1; *rt2 = (acmx / (*rt1)) * acmn - (b / (*rt1)) * b; }
  else if (sm > 0.0f) { *rt1 = 0.5f * (sm + rt); sgn1 = 1; *rt2 = (acmx / (*rt1)) * acmn - (b / (*rt1)) * b; }
  else { *rt1 = 0.5f * rt; *rt2 = -0.5f * rt; sgn1 = 1; }
  float cs; int sgn2;
  if (df >= 0.0f) { cs = df + rt; sgn2 = 1; } else { cs = df - rt; sgn2 = -1; }
  float acs = fabsf(cs);
  if (acs > ab) { float ct = -tb / cs; *sn1 = 1.0f / sqrtf(1.0f + ct * ct); *cs1 = ct * (*sn1); }
  else {
    if (ab == 0.0f) { *cs1 = 1.0f; *sn1 = 0.0f; }
    else { float tn = -cs / tb; *cs1 = 1.0f / sqrtf(1.0f + tn * tn); *sn1 = tn * (*cs1); }
  }
  if (sgn1 == sgn2) { float tn = *cs1; *cs1 = -(*sn1); *sn1 = tn; }
}

__global__ void eigen_kernel(const float* __restrict__ xwx, float* __restrict__ out) {
#pragma clang fp contract(off)
  __shared__ float A[81];
  __shared__ float Z[81];
  __shared__ float d1[10], e1[10], tauv[9], wc[10], wsn[10];
  if (threadIdx.x != 0) return;
  const int b = blockIdx.x;
  const int n = 9;
  {
    int k = 0;
    for (int i = 0; i < 9; ++i)
      for (int j = i; j < 9; ++j, ++k) {
        float v = xwx[b * 45 + k];
        A[i * 9 + j] = v;
        A[j * 9 + i] = v;
      }
  }
  for (int i = 0; i < n - 1; ++i) {
    float alpha = A[(i + 1) * 9 + i];
    float xn2 = 0.0f;
    for (int k2 = i + 2; k2 < n; ++k2) xn2 += A[k2 * 9 + i] * A[k2 * 9 + i];
    float xnorm = sqrtf(xn2);
    float taui;
    if (xnorm == 0.0f) taui = 0.0f;
    else {
      float beta = -s_sign(slapy2_(alpha, xnorm), alpha);
      taui = (beta - alpha) / beta;
      float scl = 1.0f / (alpha - beta);
      for (int k2 = i + 2; k2 < n; ++k2) A[k2 * 9 + i] *= scl;
      alpha = beta;
    }
    e1[i + 1] = alpha;
    if (taui != 0.0f) {
      float w[9];
      for (int r = i + 1; r < n; ++r) {
        float sum = A[r * 9 + (i + 1)];
        for (int k2 = i + 2; k2 < n; ++k2) sum += A[r * 9 + k2] * A[k2 * 9 + i];
        w[r] = taui * sum;
      }
      float wv_ = w[i + 1];
      for (int k2 = i + 2; k2 < n; ++k2) wv_ += w[k2] * A[k2 * 9 + i];
      float alpha2 = -0.5f * taui * wv_;
      for (int r = i + 1; r < n; ++r) w[r] += alpha2 * ((r == i + 1) ? 1.0f : A[r * 9 + i]);
      for (int r = i + 1; r < n; ++r) {
        float vr = (r == i + 1) ? 1.0f : A[r * 9 + i];
        for (int cc = i + 1; cc < n; ++cc) {
          float vc = (cc == i + 1) ? 1.0f : A[cc * 9 + i];
          A[r * 9 + cc] -= vr * w[cc] + w[r] * vc;
        }
      }
    }
    tauv[i] = taui;
  }
  for (int k2 = 0; k2 < n; ++k2) d1[k2 + 1] = A[k2 * 9 + k2];
  for (int i = 0; i < 81; ++i) Z[i] = 0.0f;
  for (int i = 0; i < 9; ++i) Z[i * 9 + i] = 1.0f;
  const float eps = 5.9604645e-08f;
  const float eps2 = eps * eps;
  const float safmin = 1.17549435e-38f;
  const int nmaxit = n * 30;
  int jtot = 0;
  int l1 = 1;
  e1[9] = 0.0f;
  while (l1 <= n) {
    if (l1 > 1) e1[l1 - 1] = 0.0f;
    int m;
    if (l1 <= n - 1) {
      for (m = l1; m <= n - 1; ++m) {
        float tst = fabsf(e1[m]);
        if (tst == 0.0f) break;
        if (tst <= (sqrtf(fabsf(d1[m])) * sqrtf(fabsf(d1[m + 1]))) * eps) { e1[m] = 0.0f; break; }
      }
    } else m = n;
    int l = l1;
    int lsv = l, lend = m, lendsv = lend;
    l1 = m + 1;
    if (lend == l) continue;
    if (fabsf(d1[lend]) < fabsf(d1[l])) { lend = lsv; l = lendsv; }
    if (lend > l) {
      while (true) {
        int mq;
        if (l != lend) {
          for (mq = l; mq <= lend - 1; ++mq) {
            float tst = e1[mq] * e1[mq];
            if (tst <= (eps2 * fabsf(d1[mq])) * fabsf(d1[mq + 1]) + safmin) break;
          }
        } else mq = lend;
        if (mq < lend) e1[mq] = 0.0f;
        float p = d1[l];
        if (mq == l) { d1[l] = p; ++l; if (l <= lend) continue; break; }
        if (mq == l + 1) {
          float rt1, rt2, cq, sq;
          slaev2_(d1[l], e1[l], d1[l + 1], &rt1, &rt2, &cq, &sq);
          for (int i = 0; i < 9; ++i) {
            float t = Z[i * 9 + l];
            Z[i * 9 + l] = cq * t - sq * Z[i * 9 + l - 1];
            Z[i * 9 + l - 1] = sq * t + cq * Z[i * 9 + l - 1];
          }
          d1[l] = rt1; d1[l + 1] = rt2; e1[l] = 0.0f;
          l += 2;
          if (l <= lend) continue;
          break;
        }
        if (jtot == nmaxit) break;
        ++jtot;
        float g = (d1[l + 1] - p) / (2.0f * e1[l]);
        float r = slapy2_(g, 1.0f);
        g = d1[mq] - p + e1[l] / (g + s_sign(r, g));
        float sq = 1.0f, cq = 1.0f;
        p = 0.0f;
        for (int i = mq - 1; i >= l; --i) {
          float f = sq * e1[i];
          float bq = cq * e1[i];
          slartg_(g, f, &cq, &sq, &r);
          if (i != mq - 1) e1[i + 1] = r;
          g = d1[i + 1] - p;
          r = (d1[i] - g) * sq + 2.0f * cq * bq;
          p = sq * r;
          d1[i + 1] = g + p;
          g = cq * r - bq;
          wc[i] = cq;
          wsn[i] = -sq;
        }
        for (int jj = mq - 1; jj >= l; --jj) {
          float cj = wc[jj], sj = wsn[jj];
          for (int i = 0; i < 9; ++i) {
            float t = Z[i * 9 + jj];
            Z[i * 9 + jj] = cj * t - sj * Z[i * 9 + jj - 1];
            Z[i * 9 + jj - 1] = sj * t + cj * Z[i * 9 + jj - 1];
          }
        }
        d1[l] -= p;
        e1[l] = g;
      }
    } else {
      while (true) {
        int mq;
        if (l != lend) {
          for (mq = l; mq >= lend + 1; --mq) {
            float tst = e1[mq - 1] * e1[mq - 1];
            if (tst <= (eps2 * fabsf(d1[mq])) * fabsf(d1[mq - 1]) + safmin) break;
          }
        } else mq = lend;
        if (mq > lend) e1[mq - 1] = 0.0f;
        float p = d1[l];
        if (mq == l) { d1[l] = p; --l; if (l >= lend) continue; break; }
        if (mq == l - 1) {
          float rt1, rt2, cq, sq;
          slaev2_(d1[l - 1], e1[l - 1], d1[l], &rt1, &rt2, &cq, &sq);
          for (int i = 0; i < 9; ++i) {
            float t = Z[i * 9 + l - 1];
            Z[i * 9 + l - 1] = cq * t - sq * Z[i * 9 + l - 2];
            Z[i * 9 + l - 2] = sq * t + cq * Z[i * 9 + l - 2];
          }
          d1[l - 1] = rt1; d1[l] = rt2; e1[l - 1] = 0.0f;
          l -= 2;
          if (l >= lend) continue;
          break;
        }
        if (jtot == nmaxit) break;
        ++jtot;
        float g = (d1[l - 1] - p) / (2.0f * e1[l - 1]);
        float r = slapy2_(g, 1.0f);
        g = d1[mq] - p + e1[l - 1] / (g + s_sign(r, g));
        float sq = 1.0f, cq = 1.0f;
        p = 0.0f;
        for (int i = mq; i <= l - 1; ++i) {
          float f = sq * e1[i];
          float bq = cq * e1[i];
          slartg_(g, f, &cq, &sq, &r);
          if (i != mq) e1[i - 1] = r;
          g = d1[i] - p;
          r = (d1[i + 1] - g) * sq + 2.0f * cq * bq;
          p = sq * r;
          d1[i] = g + p;
          g = cq * r - bq;
          wc[i] = cq;
          wsn[i] = sq;
        }
        for (int jj = mq; jj <= l - 1; ++jj) {
          float cj = wc[jj], sj = wsn[jj];
          for (int i = 0; i < 9; ++i) {
            float t = Z[i * 9 + jj];
            Z[i * 9 + jj] = cj * t - sj * Z[i * 9 + jj - 1];
            Z[i * 9 + jj - 1] = sj * t + cj * Z[i * 9 + jj - 1];
          }
        }
        d1[l] -= p;
        e1[l - 1] = g;
      }
    }
  }
  for (int ii = 2; ii <= n; ++ii) {
    int i = ii - 1, k = i;
    float p = d1[i];
    for (int j = ii; j <= n; ++j)
      if (d1[j] < p) { k = j; p = d1[j]; }
    if (k != i) {
      d1[k] = d1[i];
      d1[i] = p;
      for (int r = 0; r < 9; ++r) {
        float t = Z[r * 9 + (i - 1)];
        Z[r * 9 + (i - 1)] = Z[r * 9 + (k - 1)];
        Z[r * 9 + (k - 1)] = t;
      }
    }
  }
  float z0[9];
  for (int i = 0; i < 9; ++i) z0[i] = Z[i * 9 + 0];
  for (int i = n - 2; i >= 0; --i) {
    float taui = tauv[i];
    if (taui == 0.0f) continue;
    float sum = z0[i + 1];
    for (int k2 = i + 2; k2 < n; ++k2) sum += A[k2 * 9 + i] * z0[k2];
    sum *= taui;
    z0[i + 1] -= sum;
    for (int k2 = i + 2; k2 < n; ++k2) z0[k2] -= A[k2 * 9 + i] * sum;
  }
  float nrm = 0.0f;
  for (int i = 0; i < 9; ++i) nrm += z0[i] * z0[i];
  float q = sqrtf(nrm);
  for (int i = 0; i < 9; ++i) out[b * 9 + i] = z0[i] / q;
}

extern "C" void kernel_launch(void* const* d_in, const int* in_sizes, int n_in,
                              void* d_out, int out_size, void* d_ws, size_t ws_size,
                              hipStream_t stream) {
  const float* xc     = (const float*)d_in[0];
  const float* Wfirst = (const float*)d_in[1];
  const float* bfirst = (const float*)d_in[2];
  const float* W1s    = (const float*)d_in[3];
  const float* b1s    = (const float*)d_in[4];
  const float* W2s    = (const float*)d_in[5];
  const float* b2s    = (const float*)d_in[6];
  const float* Wfinal = (const float*)d_in[7];
  const float* bfinal = (const float*)d_in[8];

  _Float16* Whi = (_Float16*)d_ws;                       // 24*16384 = 768 KB
  _Float16* Wlo = Whi + (size_t)24 * 128 * 128;          // 768 KB (unused by mlp)
  float* partial = (float*)(Wlo + (size_t)24 * 128 * 128);  // 8192*45*4 = 1.47 MB
  float* xwx = partial + (size_t)8192 * 45;

  prep_w_kernel<<<(24 * 128 * 128 + 255) / 256, 256, 0, stream>>>(W1s, W2s, Whi, Wlo);
  mlp_xwx_kernel<<<4096, 256, 0, stream>>>(xc, Wfirst, bfirst, Whi, Wlo, b1s, b2s,
                                           Wfinal, bfinal, partial);
  reduce_xwx_kernel<<<(64 * 45 + 255) / 256, 256, 0, stream>>>(partial, xwx);
  eigen_kernel<<<64, 64, 0, stream>>>(xwx, (float*)d_out);
}

// Round 20
// 790.363 us; speedup vs baseline: 1.3256x; 1.3256x over previous
//
#include <hip/hip_runtime.h>
#include <math.h>

#define NPTS 8192
#define CHN 128
#define NLAYER 12
#define LDH 136   // fp16 LDS row stride (128 + 8): 272 B = 16-B aligned (verified layout)

typedef __attribute__((ext_vector_type(8))) _Float16 f16x8;
typedef __attribute__((ext_vector_type(4))) float f32x4;

union U2h { unsigned int u; _Float16 f[2]; };
union U4h { uint2 u; _Float16 f[4]; };

// ---- W1s/W2s fp32 -> fp16 (plain); conv c = 2*layer (W1) / 2*layer+1 (W2), [o][c] ----
__global__ void prep_w_kernel(const float* __restrict__ W1s,
                              const float* __restrict__ W2s,
                              _Float16* __restrict__ Whi) {
  int idx = blockIdx.x * 256 + threadIdx.x;
  if (idx >= 24 * 128 * 128) return;
  int conv = idx >> 14;
  int r = idx & 16383;
  const float* src = (conv & 1) ? (W2s + ((size_t)(conv >> 1) << 14))
                                : (W1s + ((size_t)(conv >> 1) << 14));
  Whi[idx] = (_Float16)src[r];
}

// ---------------- MFMA MLP + weighted Gram partials ----------------
// R20 mlp = byte-exact R14 champion (verified 715us, absmax 1.953e-3):
// 128-pt tile, grid 4096, 256 thr, wave = 32ch x 64pt (mt=2/nt=4),
// cross-phase W-register prefetch (wA/wB static dbuf), bias registers per phase.
__global__ __launch_bounds__(256, 2) void mlp_xwx_kernel(
    const float* __restrict__ xc,            // (B,4,N)
    const float* __restrict__ Wfirst,        // (128,4) fp32
    const float* __restrict__ bfirst,        // (128)
    const _Float16* __restrict__ Whi,        // (24,128,128)
    const float* __restrict__ b1s,           // (12,128)
    const float* __restrict__ b2s,           // (12,128)
    const float* __restrict__ Wfinal,        // (128)
    const float* __restrict__ bfinal,        // (1)
    float* __restrict__ partial) {           // (8192,45)
  __shared__ __align__(16) _Float16 Hh[128 * LDH];
  __shared__ __align__(16) _Float16 Yh[128 * LDH];
  __shared__ float red[4][64];
  const int tid = threadIdx.x;
  const int lane = tid & 63;
  const int wv = tid >> 6;                // 0..3
  const int l16 = lane & 15;
  const int quad = lane >> 4;
  const int o0 = wv << 5;                 // wave's 32-channel base
  const int b = blockIdx.x >> 6;          // 4096 blocks / 64 per image
  const int n0 = (blockIdx.x & 63) << 7;  // 128 points per block

  const float* xb = xc + ((size_t)b * 4) * NPTS + n0 + lane;
  float x1[2], x2[2], y1[2], y2[2];
  #pragma unroll
  for (int s = 0; s < 2; ++s) {
    x1[s] = xb[s * 64 + 0 * NPTS];
    x2[s] = xb[s * 64 + 1 * NPTS];
    y1[s] = xb[s * 64 + 2 * NPTS];
    y2[s] = xb[s * 64 + 3 * NPTS];
  }

  // A-frag base: W[o0 + l16 + 16*mt][quad*8 + 32*kt + j]
  const size_t arow = (size_t)(o0 + l16) * CHN + (size_t)quad * 8;

  // ---- W/bias register double-buffer; prologue loads W1[0]+b1[0] ----
  f16x8 wA[2][4], wB[2][4];
  f32x4 b1v[2], b2v[2];
  {
    const _Float16* W1h = Whi;
    #pragma unroll
    for (int mt = 0; mt < 2; ++mt) {
      #pragma unroll
      for (int kt = 0; kt < 4; ++kt)
        wA[mt][kt] = *(const f16x8*)(W1h + arow + (size_t)mt * 16 * CHN + kt * 32);
      b1v[mt] = *(const f32x4*)(b1s + o0 + mt * 16 + quad * 4);
    }
  }

  // ---- first layer (4 -> 128) on VALU fp32, both sub-tiles ----
  #pragma unroll
  for (int s = 0; s < 2; ++s) {
    #pragma unroll
    for (int j = 0; j < 32; j += 2) {
      int c = o0 + j;
      float h0 = bfirst[c] + Wfirst[c * 4 + 0] * x1[s] + Wfirst[c * 4 + 1] * x2[s] +
                 Wfirst[c * 4 + 2] * y1[s] + Wfirst[c * 4 + 3] * y2[s];
      float h1 = bfirst[c + 1] + Wfirst[(c + 1) * 4 + 0] * x1[s] + Wfirst[(c + 1) * 4 + 1] * x2[s] +
                 Wfirst[(c + 1) * 4 + 2] * y1[s] + Wfirst[(c + 1) * 4 + 3] * y2[s];
      U2h ph;
      ph.f[0] = (_Float16)h0;
      ph.f[1] = (_Float16)h1;
      *(unsigned int*)&Hh[(s * 64 + lane) * LDH + c] = ph.u;
    }
  }
  __syncthreads();

  for (int layer = 0; layer < NLAYER; ++layer) {
    // ========== conv1 (uses wA/b1v, preloaded); prefetch wB = W2[layer], b2v ==========
    {
      const _Float16* W2h = Whi + ((size_t)(2 * layer + 1) << 14);
      #pragma unroll
      for (int mt = 0; mt < 2; ++mt) {
        #pragma unroll
        for (int kt = 0; kt < 4; ++kt)
          wB[mt][kt] = *(const f16x8*)(W2h + arow + (size_t)mt * 16 * CHN + kt * 32);
        b2v[mt] = *(const f32x4*)(b2s + layer * CHN + o0 + mt * 16 + quad * 4);
      }
    }
    #pragma unroll
    for (int s = 0; s < 2; ++s) {
      f32x4 acc[2][4];
      #pragma unroll
      for (int mt = 0; mt < 2; ++mt)
        #pragma unroll
        for (int nt = 0; nt < 4; ++nt) acc[mt][nt] = b1v[mt];
      #pragma unroll
      for (int kt = 0; kt < 4; ++kt) {
        #pragma unroll
        for (int nt = 0; nt < 4; ++nt) {
          f16x8 bh = *(const f16x8*)&Hh[(s * 64 + nt * 16 + l16) * LDH + kt * 32 + quad * 8];
          #pragma unroll
          for (int mt = 0; mt < 2; ++mt)
            acc[mt][nt] = __builtin_amdgcn_mfma_f32_16x16x32_f16(wA[mt][kt], bh, acc[mt][nt], 0, 0, 0);
        }
      }
      #pragma unroll
      for (int mt = 0; mt < 2; ++mt)
        #pragma unroll
        for (int nt = 0; nt < 4; ++nt) {
          int p = s * 64 + nt * 16 + l16;
          int c = o0 + mt * 16 + quad * 4;
          U4h ph;
          #pragma unroll
          for (int r = 0; r < 4; ++r)
            ph.f[r] = (_Float16)fmaxf(acc[mt][nt][r], 0.0f);
          *(uint2*)&Yh[p * LDH + c] = ph.u;
        }
    }
    __syncthreads();
    // ========== conv2 (uses wB/b2v); prefetch wA = W1[layer+1], b1v ==========
    if (layer + 1 < NLAYER) {
      const _Float16* W1h = Whi + ((size_t)(2 * layer + 2) << 14);
      #pragma unroll
      for (int mt = 0; mt < 2; ++mt) {
        #pragma unroll
        for (int kt = 0; kt < 4; ++kt)
          wA[mt][kt] = *(const f16x8*)(W1h + arow + (size_t)mt * 16 * CHN + kt * 32);
        b1v[mt] = *(const f32x4*)(b1s + (layer + 1) * CHN + o0 + mt * 16 + quad * 4);
      }
    }
    #pragma unroll
    for (int s = 0; s < 2; ++s) {
      f32x4 acc[2][4];
      #pragma unroll
      for (int mt = 0; mt < 2; ++mt)
        #pragma unroll
        for (int nt = 0; nt < 4; ++nt) acc[mt][nt] = b2v[mt];
      #pragma unroll
      for (int kt = 0; kt < 4; ++kt) {
        #pragma unroll
        for (int nt = 0; nt < 4; ++nt) {
          f16x8 bh = *(const f16x8*)&Yh[(s * 64 + nt * 16 + l16) * LDH + kt * 32 + quad * 8];
          #pragma unroll
          for (int mt = 0; mt < 2; ++mt)
            acc[mt][nt] = __builtin_amdgcn_mfma_f32_16x16x32_f16(wB[mt][kt], bh, acc[mt][nt], 0, 0, 0);
        }
      }
      #pragma unroll
      for (int mt = 0; mt < 2; ++mt)
        #pragma unroll
        for (int nt = 0; nt < 4; ++nt) {
          int p = s * 64 + nt * 16 + l16;
          int c = o0 + mt * 16 + quad * 4;
          U4h oh;
          oh.u = *(const uint2*)&Hh[p * LDH + c];
          U4h ph;
          #pragma unroll
          for (int r = 0; r < 4; ++r) {
            float v = fmaxf((float)oh.f[r] + acc[mt][nt][r], 0.0f);
            ph.f[r] = (_Float16)v;
          }
          *(uint2*)&Hh[p * LDH + c] = ph.u;
        }
    }
    __syncthreads();
  }

  // ---- final conv (128 -> 1) + weighted Gram, per sub-tile ----
  #pragma unroll
  for (int s = 0; s < 2; ++s) {
    {
      float part = 0.0f;
      #pragma unroll
      for (int j = 0; j < 4; ++j) {
        f16x8 kh = *(const f16x8*)&Hh[(s * 64 + lane) * LDH + o0 + j * 8];
        #pragma unroll
        for (int e = 0; e < 8; ++e)
          part = fmaf(Wfinal[o0 + j * 8 + e], (float)kh[e], part);
      }
      red[wv][lane] = part;
    }
    __syncthreads();
    if (wv == 0) {
      float logit = red[0][lane] + red[1][lane] + red[2][lane] + red[3][lane] + bfinal[0];
      float wgt = fmaxf(tanhf(logit), 0.0f);
      float X[9] = {y1[s] * x1[s], y1[s] * x2[s], y1[s], y2[s] * x1[s], y2[s] * x2[s], y2[s],
                    x1[s], x2[s], 1.0f};
      int k = 0;
      #pragma unroll
      for (int i = 0; i < 9; ++i) {
        #pragma unroll
        for (int j = i; j < 9; ++j) {
          float v = wgt * X[i] * X[j];
          #pragma unroll
          for (int off = 32; off > 0; off >>= 1) v += __shfl_down(v, off, 64);
          if (lane == 0) partial[((size_t)blockIdx.x * 2 + s) * 45 + k] = v;
          ++k;
        }
      }
    }
    __syncthreads();   // red reused by next sub-tile
  }
}

// -------- faithful LAPACK fp32 ssyevd path for 9x9 (ssytd2 + ssteqr('I') + Q) --------
__device__ inline float s_sign(float a, float b) { return (b >= 0.0f) ? fabsf(a) : -fabsf(a); }

__device__ inline float slapy2_(float x, float y) {
#pragma clang fp contract(off)
  float ax = fabsf(x), ay = fabsf(y);
  float w = ax > ay ? ax : ay;
  float z = ax > ay ? ay : ax;
  if (z == 0.0f) return w;
  float t = z / w;
  return w * sqrtf(1.0f + t * t);
}

// LAPACK >= 3.10 slartg (c >= 0 convention), fast path
__device__ inline void slartg_(float f, float g, float* c, float* s, float* r) {
#pragma clang fp contract(off)
  if (g == 0.0f) { *c = 1.0f; *s = 0.0f; *r = f; }
  else if (f == 0.0f) { *c = 0.0f; *s = s_sign(1.0f, g); *r = fabsf(g); }
  else {
    float f1 = fabsf(f);
    float d = sqrtf(f * f + g * g);
    *c = f1 / d;
    *r = s_sign(d, f);
    *s = g / (*r);
  }
}

__device__ void slaev2_(float a, float b, float c, float* rt1, float* rt2,
                        float* cs1, float* sn1) {
#pragma clang fp contract(off)
  float sm = a + c, df = a - c, adf = fabsf(df), tb = b + b, ab = fabsf(tb);
  float acmx, acmn;
  if (fabsf(a) > fabsf(c)) { acmx = a; acmn = c; } else { acmx = c; acmn = a; }
  float rt;
  if (adf > ab) { float t = ab / adf; rt = adf * sqrtf(1.0f + t * t); }
  else if (adf < ab) { float t = adf / ab; rt = ab * sqrtf(1.0f + t * t); }
  else rt = ab * sqrtf(2.0f);
  int sgn1;
  if (sm < 0.0f) { *rt1 = 0.5f * (sm - rt); sgn1 = -1; *rt2 = (acmx / (*rt1)) * acmn - (b / (*rt1)) * b; }
  else if (sm > 0.0f) { *rt1 = 0.5f * (sm + rt); sgn1 = 1; *rt2 = (acmx / (*rt1)) * acmn - (b / (*rt1)) * b; }
  else { *rt1 = 0.5f * rt; *rt2 = -0.5f * rt; sgn1 = 1; }
  float cs; int sgn2;
  if (df >= 0.0f) { cs = df + rt; sgn2 = 1; } else { cs = df - rt; sgn2 = -1; }
  float acs = fabsf(cs);
  if (acs > ab) { float ct = -tb / cs; *sn1 = 1.0f / sqrtf(1.0f + ct * ct); *cs1 = ct * (*sn1); }
  else {
    if (ab == 0.0f) { *cs1 = 1.0f; *sn1 = 0.0f; }
    else { float tn = -cs / tb; *cs1 = 1.0f / sqrtf(1.0f + tn * tn); *sn1 = tn * (*cs1); }
  }
  if (sgn1 == sgn2) { float tn = *cs1; *cs1 = -(*sn1); *sn1 = tn; }
}

// Fused: per-b deterministic partial reduction (threads 0..44, fixed blk order,
// bit-identical to the old reduce_xwx_kernel) + 9x9 eigensolve on thread 0.
__global__ void eigen_kernel(const float* __restrict__ partial, float* __restrict__ out) {
#pragma clang fp contract(off)
  __shared__ float xwxS[45];
  __shared__ float A[81];
  __shared__ float Z[81];
  __shared__ float d1[10], e1[10], tauv[9], wc[10], wsn[10];
  const int b = blockIdx.x;
  {
    int t = threadIdx.x;
    if (t < 45) {
      float s = 0.0f;
      for (int blk = 0; blk < 128; ++blk)
        s += partial[((size_t)b * 128 + blk) * 45 + t];
      xwxS[t] = s;
    }
  }
  __syncthreads();
  if (threadIdx.x != 0) return;
  const int n = 9;
  {
    int k = 0;
    for (int i = 0; i < 9; ++i)
      for (int j = i; j < 9; ++j, ++k) {
        float v = xwxS[k];
        A[i * 9 + j] = v;
        A[j * 9 + i] = v;
      }
  }
  for (int i = 0; i < n - 1; ++i) {
    float alpha = A[(i + 1) * 9 + i];
    float xn2 = 0.0f;
    for (int k2 = i + 2; k2 < n; ++k2) xn2 += A[k2 * 9 + i] * A[k2 * 9 + i];
    float xnorm = sqrtf(xn2);
    float taui;
    if (xnorm == 0.0f) taui = 0.0f;
    else {
      float beta = -s_sign(slapy2_(alpha, xnorm), alpha);
      taui = (beta - alpha) / beta;
      float scl = 1.0f / (alpha - beta);
      for (int k2 = i + 2; k2 < n; ++k2) A[k2 * 9 + i] *= scl;
      alpha = beta;
    }
    e1[i + 1] = alpha;
    if (taui != 0.0f) {
      float w[9];
      for (int r = i + 1; r < n; ++r) {
        float sum = A[r * 9 + (i + 1)];
        for (int k2 = i + 2; k2 < n; ++k2) sum += A[r * 9 + k2] * A[k2 * 9 + i];
        w[r] = taui * sum;
      }
      float wv_ = w[i + 1];
      for (int k2 = i + 2; k2 < n; ++k2) wv_ += w[k2] * A[k2 * 9 + i];
      float alpha2 = -0.5f * taui * wv_;
      for (int r = i + 1; r < n; ++r) w[r] += alpha2 * ((r == i + 1) ? 1.0f : A[r * 9 + i]);
      for (int r = i + 1; r < n; ++r) {
        float vr = (r == i + 1) ? 1.0f : A[r * 9 + i];
        for (int cc = i + 1; cc < n; ++cc) {
          float vc = (cc == i + 1) ? 1.0f : A[cc * 9 + i];
          A[r * 9 + cc] -= vr * w[cc] + w[r] * vc;
        }
      }
    }
    tauv[i] = taui;
  }
  for (int k2 = 0; k2 < n; ++k2) d1[k2 + 1] = A[k2 * 9 + k2];
  for (int i = 0; i < 81; ++i) Z[i] = 0.0f;
  for (int i = 0; i < 9; ++i) Z[i * 9 + i] = 1.0f;
  const float eps = 5.9604645e-08f;
  const float eps2 = eps * eps;
  const float safmin = 1.17549435e-38f;
  const int nmaxit = n * 30;
  int jtot = 0;
  int l1 = 1;
  e1[9] = 0.0f;
  while (l1 <= n) {
    if (l1 > 1) e1[l1 - 1] = 0.0f;
    int m;
    if (l1 <= n - 1) {
      for (m = l1; m <= n - 1; ++m) {
        float tst = fabsf(e1[m]);
        if (tst == 0.0f) break;
        if (tst <= (sqrtf(fabsf(d1[m])) * sqrtf(fabsf(d1[m + 1]))) * eps) { e1[m] = 0.0f; break; }
      }
    } else m = n;
    int l = l1;
    int lsv = l, lend = m, lendsv = lend;
    l1 = m + 1;
    if (lend == l) continue;
    if (fabsf(d1[lend]) < fabsf(d1[l])) { lend = lsv; l = lendsv; }
    if (lend > l) {
      while (true) {
        int mq;
        if (l != lend) {
          for (mq = l; mq <= lend - 1; ++mq) {
            float tst = e1[mq] * e1[mq];
            if (tst <= (eps2 * fabsf(d1[mq])) * fabsf(d1[mq + 1]) + safmin) break;
          }
        } else mq = lend;
        if (mq < lend) e1[mq] = 0.0f;
        float p = d1[l];
        if (mq == l) { d1[l] = p; ++l; if (l <= lend) continue; break; }
        if (mq == l + 1) {
          float rt1, rt2, cq, sq;
          slaev2_(d1[l], e1[l], d1[l + 1], &rt1, &rt2, &cq, &sq);
          for (int i = 0; i < 9; ++i) {
            float t = Z[i * 9 + l];
            Z[i * 9 + l] = cq * t - sq * Z[i * 9 + l - 1];
            Z[i * 9 + l - 1] = sq * t + cq * Z[i * 9 + l - 1];
          }
          d1[l] = rt1; d1[l + 1] = rt2; e1[l] = 0.0f;
          l += 2;
          if (l <= lend) continue;
          break;
        }
        if (jtot == nmaxit) break;
        ++jtot;
        float g = (d1[l + 1] - p) / (2.0f * e1[l]);
        float r = slapy2_(g, 1.0f);
        g = d1[mq] - p + e1[l] / (g + s_sign(r, g));
        float sq = 1.0f, cq = 1.0f;
        p = 0.0f;
        for (int i = mq - 1; i >= l; --i) {
          float f = sq * e1[i];
          float bq = cq * e1[i];
          slartg_(g, f, &cq, &sq, &r);
          if (i != mq - 1) e1[i + 1] = r;
          g = d1[i + 1] - p;
          r = (d1[i] - g) * sq + 2.0f * cq * bq;
          p = sq * r;
          d1[i + 1] = g + p;
          g = cq * r - bq;
          wc[i] = cq;
          wsn[i] = -sq;
        }
        for (int jj = mq - 1; jj >= l; --jj) {
          float cj = wc[jj], sj = wsn[jj];
          for (int i = 0; i < 9; ++i) {
            float t = Z[i * 9 + jj];
            Z[i * 9 + jj] = cj * t - sj * Z[i * 9 + jj - 1];
            Z[i * 9 + jj - 1] = sj * t + cj * Z[i * 9 + jj - 1];
          }
        }
        d1[l] -= p;
        e1[l] = g;
      }
    } else {
      while (true) {
        int mq;
        if (l != lend) {
          for (mq = l; mq >= lend + 1; --mq) {
            float tst = e1[mq - 1] * e1[mq - 1];
            if (tst <= (eps2 * fabsf(d1[mq])) * fabsf(d1[mq - 1]) + safmin) break;
          }
        } else mq = lend;
        if (mq > lend) e1[mq - 1] = 0.0f;
        float p = d1[l];
        if (mq == l) { d1[l] = p; --l; if (l >= lend) continue; break; }
        if (mq == l - 1) {
          float rt1, rt2, cq, sq;
          slaev2_(d1[l - 1], e1[l - 1], d1[l], &rt1, &rt2, &cq, &sq);
          for (int i = 0; i < 9; ++i) {
            float t = Z[i * 9 + l - 1];
            Z[i * 9 + l - 1] = cq * t - sq * Z[i * 9 + l - 2];
            Z[i * 9 + l - 2] = sq * t + cq * Z[i * 9 + l - 2];
          }
          d1[l - 1] = rt1; d1[l] = rt2; e1[l - 1] = 0.0f;
          l -= 2;
          if (l >= lend) continue;
          break;
        }
        if (jtot == nmaxit) break;
        ++jtot;
        float g = (d1[l - 1] - p) / (2.0f * e1[l - 1]);
        float r = slapy2_(g, 1.0f);
        g = d1[mq] - p + e1[l - 1] / (g + s_sign(r, g));
        float sq = 1.0f, cq = 1.0f;
        p = 0.0f;
        for (int i = mq; i <= l - 1; ++i) {
          float f = sq * e1[i];
          float bq = cq * e1[i];
          slartg_(g, f, &cq, &sq, &r);
          if (i != mq) e1[i - 1] = r;
          g = d1[i] - p;
          r = (d1[i + 1] - g) * sq + 2.0f * cq * bq;
          p = sq * r;
          d1[i] = g + p;
          g = cq * r - bq;
          wc[i] = cq;
          wsn[i] = sq;
        }
        for (int jj = mq; jj <= l - 1; ++jj) {
          float cj = wc[jj], sj = wsn[jj];
          for (int i = 0; i < 9; ++i) {
            float t = Z[i * 9 + jj];
            Z[i * 9 + jj] = cj * t - sj * Z[i * 9 + jj - 1];
            Z[i * 9 + jj - 1] = sj * t + cj * Z[i * 9 + jj - 1];
          }
        }
        d1[l] -= p;
        e1[l - 1] = g;
      }
    }
  }
  for (int ii = 2; ii <= n; ++ii) {
    int i = ii - 1, k = i;
    float p = d1[i];
    for (int j = ii; j <= n; ++j)
      if (d1[j] < p) { k = j; p = d1[j]; }
    if (k != i) {
      d1[k] = d1[i];
      d1[i] = p;
      for (int r = 0; r < 9; ++r) {
        float t = Z[r * 9 + (i - 1)];
        Z[r * 9 + (i - 1)] = Z[r * 9 + (k - 1)];
        Z[r * 9 + (k - 1)] = t;
      }
    }
  }
  float z0[9];
  for (int i = 0; i < 9; ++i) z0[i] = Z[i * 9 + 0];
  for (int i = n - 2; i >= 0; --i) {
    float taui = tauv[i];
    if (taui == 0.0f) continue;
    float sum = z0[i + 1];
    for (int k2 = i + 2; k2 < n; ++k2) sum += A[k2 * 9 + i] * z0[k2];
    sum *= taui;
    z0[i + 1] -= sum;
    for (int k2 = i + 2; k2 < n; ++k2) z0[k2] -= A[k2 * 9 + i] * sum;
  }
  float nrm = 0.0f;
  for (int i = 0; i < 9; ++i) nrm += z0[i] * z0[i];
  float q = sqrtf(nrm);
  for (int i = 0; i < 9; ++i) out[b * 9 + i] = z0[i] / q;
}

extern "C" void kernel_launch(void* const* d_in, const int* in_sizes, int n_in,
                              void* d_out, int out_size, void* d_ws, size_t ws_size,
                              hipStream_t stream) {
  const float* xc     = (const float*)d_in[0];
  const float* Wfirst = (const float*)d_in[1];
  const float* bfirst = (const float*)d_in[2];
  const float* W1s    = (const float*)d_in[3];
  const float* b1s    = (const float*)d_in[4];
  const float* W2s    = (const float*)d_in[5];
  const float* b2s    = (const float*)d_in[6];
  const float* Wfinal = (const float*)d_in[7];
  const float* bfinal = (const float*)d_in[8];

  _Float16* Whi = (_Float16*)d_ws;                          // 24*16384*2B = 768 KB
  float* partial = (float*)(Whi + (size_t)24 * 128 * 128);  // 8192*45*4 = 1.47 MB

  prep_w_kernel<<<(24 * 128 * 128 + 255) / 256, 256, 0, stream>>>(W1s, W2s, Whi);
  mlp_xwx_kernel<<<4096, 256, 0, stream>>>(xc, Wfirst, bfirst, Whi, b1s, b2s,
                                           Wfinal, bfinal, partial);
  eigen_kernel<<<64, 64, 0, stream>>>(partial, (float*)d_out);
}